// Round 14
// baseline (2816.274 us; speedup 1.0000x reference)
//
#include <hip/hip_runtime.h>
#include <math.h>

// ---- static problem config (matches reference) ----
namespace {
constexpr int N  = 102400;   // nodes
constexpr int E  = 819200;   // edges
constexpr int B_ = 16;       // graphs
constexpr int G  = 72;       // voxel cells per graph (8 x 9)
constexpr int GX = 8;
constexpr int NB = N / 256;  // 400 blocks over nodes
constexpr int EB = E / 256;  // 3200 blocks over edges
}

// ================= CSR build =================

__global__ __launch_bounds__(256) void count_kernel(const int* __restrict__ ei,
                                                    int* __restrict__ cnt) {
  int e = blockIdx.x * 256 + threadIdx.x;
  atomicAdd(&cnt[ei[E + e]], 1);
}

__global__ __launch_bounds__(256) void rcnt_kernel(const int* __restrict__ cnt,
                                                   float* __restrict__ rcnt) {
  int n = blockIdx.x * 256 + threadIdx.x;
  rcnt[n] = 1.0f / (float)max(cnt[n], 1);
}

// per-256-chunk sums of cnt
__global__ __launch_bounds__(256) void reduce_cnt(const int* __restrict__ cnt,
                                                  int* __restrict__ bsum) {
  __shared__ int s[256];
  int i = blockIdx.x * 256 + threadIdx.x;
  s[threadIdx.x] = cnt[i];
  __syncthreads();
  for (int st = 128; st > 0; st >>= 1) {
    if (threadIdx.x < st) s[threadIdx.x] += s[threadIdx.x + st];
    __syncthreads();
  }
  if (threadIdx.x == 0) bsum[blockIdx.x] = s[0];
}

// single-block exclusive scan of the NB block sums
__global__ __launch_bounds__(512) void scan_bsum(const int* __restrict__ bsum,
                                                 int* __restrict__ boff) {
  __shared__ int s[512];
  int i = threadIdx.x;
  int v = (i < NB) ? bsum[i] : 0;
  s[i] = v;
  __syncthreads();
  for (int st = 1; st < 512; st <<= 1) {
    int t = (i >= st) ? s[i - st] : 0;
    __syncthreads();
    s[i] += t;
    __syncthreads();
  }
  if (i < NB) boff[i] = s[i] - v;  // exclusive
}

// rowptr[n] = exclusive scan of cnt; cursor = rowptr; sdesc[n] = (beg, end)
__global__ __launch_bounds__(256) void write_rowptr(const int* __restrict__ cnt,
                                                    const int* __restrict__ boff,
                                                    int* __restrict__ rowptr,
                                                    int* __restrict__ cursor,
                                                    int2* __restrict__ sdesc) {
  __shared__ int s[256];
  int i = blockIdx.x * 256 + threadIdx.x;
  int v = cnt[i];
  s[threadIdx.x] = v;
  __syncthreads();
  for (int st = 1; st < 256; st <<= 1) {
    int t = (threadIdx.x >= st) ? s[threadIdx.x - st] : 0;
    __syncthreads();
    s[threadIdx.x] += t;
    __syncthreads();
  }
  int off = boff[blockIdx.x] + s[threadIdx.x] - v;  // exclusive
  rowptr[i] = off;
  cursor[i] = off;
  sdesc[i] = make_int2(off, off + v);
  if (i == N - 1) rowptr[N] = off + v;
}

// scatter edge records (src + clamped pseudo-coords) into CSR order
__global__ __launch_bounds__(256) void edge_scatter(const int* __restrict__ ei,
                                                    const float* __restrict__ ea,
                                                    int* __restrict__ cursor,
                                                    float4* __restrict__ rec) {
  int e = blockIdx.x * 256 + threadIdx.x;
  int src = ei[e];
  int dst = ei[E + e];
  float u0 = fminf(fmaxf(ea[3 * e + 0], 0.f), 1.f);
  float u1 = fminf(fmaxf(ea[3 * e + 1], 0.f), 1.f);
  float u2 = fminf(fmaxf(ea[3 * e + 2], 0.f), 1.f);
  int slot = atomicAdd(&cursor[dst], 1);
  rec[slot] = make_float4(__int_as_float(src), u0, u1, u2);
}

// ================= pooling helper =================
__device__ __forceinline__ void atomicMaxFloat(float* addr, float val) {
  if (val >= 0.f)
    atomicMax(reinterpret_cast<int*>(addr), __float_as_int(val));
  else
    atomicMin(reinterpret_cast<unsigned int*>(addr), __float_as_uint(val));
}

// ====== LDS-bridged factored spline conv (v9 = v6 + mul-init; RECOVERY) ======
// out[n] = (1/deg) * sum_k ( sum_{e->n} b_k(e) * x_src(e) ) @ W[k]
//
// v6 (round-11, 636us best) restored exactly:
//  - __syncthreads KEPT: it doubles as a scheduling fence. Removing it (r13)
//    let the compiler hoist phase-2 loads into phase 1 -> spill storm
//    (FETCH 895MB, 2805us). Do not remove.
//  - ballot guard on 2nd edge slot NOT used (r12: serialized pipeline, 163us).
//  - only retained micro-opt: first-slot MUL-init (branch-free, -32 movs/rep).
template <int CIN, int COUT, bool RES, bool POOL>
__global__ __launch_bounds__(256, 4) void node_conv_v9(
    const float* __restrict__ X, const float* __restrict__ W,
    const float4* __restrict__ rec, const int2* __restrict__ sdesc,
    const float* __restrict__ rcnt, const float* __restrict__ res,
    float* __restrict__ Y, const float* __restrict__ pos,
    const int* __restrict__ batch, float* __restrict__ pooled) {
  constexpr int TPN  = COUT / 4;                    // phase-2 threads per node
  constexpr int NPB  = 256 / TPN;                   // nodes per block
  constexpr int ROWF = (CIN >= 8) ? 8 * CIN : 12;   // LDS floats per node row

  __shared__ float sAgg[NPB * ROWF];

  const int tid  = threadIdx.x;
  const int wave = tid >> 6;
  const int lane = tid & 63;

  // XCD swizzle: consecutive node chunks land on one XCD (L2 locality)
  const int sb = (blockIdx.x & 7) * (gridDim.x >> 3) + (blockIdx.x >> 3);
  const int nbase = sb * NPB;

  // ---- phase-2 epilogue gathers hoisted to top (coalesced) ----
  const int node_l = tid / TPN;
  const int co4 = tid % TPN;
  const int n2 = nbase + node_l;
  const float rc = rcnt[n2];
  float4 rres = make_float4(0.f, 0.f, 0.f, 0.f);
  if constexpr (RES)
    rres = *reinterpret_cast<const float4*>(res + (size_t)n2 * COUT + co4 * 4);
  float p0 = 0.f, p1 = 0.f;
  int bi = 0;
  if constexpr (POOL) {
    p0 = pos[n2 * 3 + 0];
    p1 = pos[n2 * 3 + 1];
    bi = batch[n2];
  }

  // ---------------- phase 1 ----------------
  if constexpr (CIN >= 8) {
    constexpr int QN   = CIN / 4;          // channel quads per row
    constexpr int LPN  = 8 * QN;           // lanes per node
    constexpr int NPW  = 64 / LPN;         // nodes per wave per rep
    constexpr int REPS = NPB / (4 * NPW);  // reps per wave

    const int ci4  = lane % QN;
    const int esub = (lane / QN) & 7;
    const int ns   = lane / LPN;
    const int kstar = ((lane / QN) & 1) * 4 + ((lane / (2 * QN)) & 1) * 2 +
                      ((lane / (4 * QN)) & 1);
    const int slot0 = wave * (REPS * NPW) + ns;  // local slot of rep 0

    auto loadDesc = [&](int rep) -> int2 {
      int r = min(rep, REPS - 1);
      return sdesc[nbase + slot0 + r * NPW];
    };
    auto loadRec = [&](int e) -> float4 { return rec[min(e, E - 1)]; };
    auto loadX = [&](const float4& r) -> float4 {
      int src = __float_as_int(r.x);
      return *(reinterpret_cast<const float4*>(X + (size_t)src * CIN) + ci4);
    };
    auto basis = [&](const float4& r, bool valid, float (&b)[8]) {
      float uy = r.y, uz = r.z, uw = r.w;
      float py = 1.f - uy, pz = 1.f - uz, pw = 1.f - uw;
      float g = valid ? 1.f : 0.f;
      float t0 = py * pz * g, t1 = uy * pz * g;
      float t2 = py * uz * g, t3 = uy * uz * g;
      b[0] = t0 * pw; b[1] = t1 * pw; b[2] = t2 * pw; b[3] = t3 * pw;
      b[4] = t0 * uw; b[5] = t1 * uw; b[6] = t2 * uw; b[7] = t3 * uw;
    };

    // pipeline prologue
    int2 d0 = loadDesc(0);
    int2 d1 = loadDesc(1);
    int2 d2 = loadDesc(2);
    float4 ra0 = loadRec(d0.x + esub), rb0 = loadRec(d0.x + esub + 8);
    float4 ra1 = loadRec(d1.x + esub), rb1 = loadRec(d1.x + esub + 8);
    float4 xa0 = loadX(ra0), xb0 = loadX(rb0);

#pragma unroll 1
    for (int rep = 0; rep < REPS; rep++) {
      // issue next-rep x pair (recs arrived one rep ago)
      float4 xa1 = loadX(ra1), xb1 = loadX(rb1);
      // issue rep+2 rec pair (desc arrived one rep ago)
      float4 ra2 = loadRec(d2.x + esub), rb2 = loadRec(d2.x + esub + 8);
      // issue rep+3 desc
      int2 d3 = loadDesc(rep + 3);

      float agg[32];

      // first slot: MUL-init (validity folded into basis) — no 32-mov init
      {
        float b[8];
        basis(ra0, d0.x + esub < d0.y, b);
#pragma unroll
        for (int k = 0; k < 8; k++) {
          agg[k * 4 + 0] = b[k] * xa0.x;
          agg[k * 4 + 1] = b[k] * xa0.y;
          agg[k * 4 + 2] = b[k] * xa0.z;
          agg[k * 4 + 3] = b[k] * xa0.w;
        }
      }
      // second slot (edges 8..15), unconditional
      {
        float b[8];
        basis(rb0, d0.x + esub + 8 < d0.y, b);
#pragma unroll
        for (int k = 0; k < 8; k++) {
          agg[k * 4 + 0] = fmaf(b[k], xb0.x, agg[k * 4 + 0]);
          agg[k * 4 + 1] = fmaf(b[k], xb0.y, agg[k * 4 + 1]);
          agg[k * 4 + 2] = fmaf(b[k], xb0.z, agg[k * 4 + 2]);
          agg[k * 4 + 3] = fmaf(b[k], xb0.w, agg[k * 4 + 3]);
        }
      }
      // rare: deg > 16 (P ~ 0.4%), exposed-latency fallback
#pragma unroll 1
      for (int e = d0.x + esub + 16; e < d0.y; e += 8) {
        float4 rr = rec[e];
        float4 xx = loadX(rr);
        float b[8];
        basis(rr, true, b);
#pragma unroll
        for (int k = 0; k < 8; k++) {
          agg[k * 4 + 0] = fmaf(b[k], xx.x, agg[k * 4 + 0]);
          agg[k * 4 + 1] = fmaf(b[k], xx.y, agg[k * 4 + 1]);
          agg[k * 4 + 2] = fmaf(b[k], xx.z, agg[k * 4 + 2]);
          agg[k * 4 + 3] = fmaf(b[k], xx.w, agg[k * 4 + 3]);
        }
      }

      // reduce-and-split over esub bits; payload 32 -> 16 -> 8 -> 4
#pragma unroll
      for (int s = 0; s < 3; s++) {
        const int m = QN << s;
        const int H = 16 >> s;
        bool up = (lane & m) != 0;
#pragma unroll
        for (int i = 0; i < H; i++) {
          float keep = up ? agg[i + H] : agg[i];
          float send = up ? agg[i] : agg[i + H];
          agg[i] = keep + __shfl_xor(send, m, 64);
        }
      }

      const int sl = slot0 + rep * NPW;
      const int idx4 = (kstar * QN + ci4) ^ (sl & 7);  // block swizzle
      *reinterpret_cast<float4*>(&sAgg[sl * ROWF + idx4 * 4]) =
          make_float4(agg[0], agg[1], agg[2], agg[3]);

      // rotate pipeline
      d0 = d1; d1 = d2; d2 = d3;
      ra0 = ra1; rb0 = rb1; ra1 = ra2; rb1 = rb2;
      xa0 = xa1; xb0 = xb1;
    }
  } else {
    // CIN == 1: lane = (node_sub, k); serial edge walk with prefetch
    constexpr int LPN  = 8;
    constexpr int NPW  = 8;
    constexpr int REPS = NPB / (4 * NPW);
    const int ns = lane / LPN;
    const int k  = lane & 7;
    const int slotbase = nbase + wave * (REPS * NPW) + ns;

    int2 seC = sdesc[slotbase];
    int2 seN = (REPS > 1) ? sdesc[slotbase + NPW] : seC;
    float4 rcC = make_float4(0.f, 0.f, 0.f, 0.f);
    bool vC = seC.x < seC.y;
    if (vC) rcC = rec[seC.x];

#pragma unroll 1
    for (int rep = 0; rep < REPS; rep++) {
      bool vN = (rep + 1 < REPS) && (seN.x < seN.y);
      float4 rcN = make_float4(0.f, 0.f, 0.f, 0.f);
      if (vN) rcN = rec[seN.x];
      int2 seNN = (rep + 2 < REPS) ? sdesc[slotbase + (rep + 2) * NPW] : seN;

      float a0 = 0.f;
      if (vC) {
        float4 r = rcC;
        int e = seC.x + 1;
        while (true) {
          bool more = e < seC.y;
          float4 rn = r;
          if (more) rn = rec[e];
          int src = __float_as_int(r.x);
          float f0 = (k & 1) ? r.y : 1.f - r.y;
          float f1 = (k & 2) ? r.z : 1.f - r.z;
          float f2 = (k & 4) ? r.w : 1.f - r.w;
          a0 = fmaf(f0 * f1 * f2, X[src], a0);
          if (!more) break;
          r = rn;
          e++;
        }
      }

      const int sl = wave * (REPS * NPW) + rep * NPW + ns;
      sAgg[sl * ROWF + k] = a0;

      seC = seN;
      seN = seNN;
      vC = vN;
      rcC = rcN;
    }
  }
  __syncthreads();  // thread fence AND scheduling fence (r13 lesson)

  // ---------------- phase 2 ----------------
  float4 acc = make_float4(0.f, 0.f, 0.f, 0.f);
  const float4* W4 = reinterpret_cast<const float4*>(W);
  const float* arow = &sAgg[node_l * ROWF];

  if constexpr (CIN == 1) {
#pragma unroll
    for (int kk = 0; kk < 8; kk++) {
      float a = arow[kk];
      float4 w = W4[kk * TPN + co4];
      acc.x = fmaf(a, w.x, acc.x);
      acc.y = fmaf(a, w.y, acc.y);
      acc.z = fmaf(a, w.z, acc.z);
      acc.w = fmaf(a, w.w, acc.w);
    }
  } else {
    constexpr int Q = CIN / 4;
    const int swz = node_l & 7;
#pragma unroll 2
    for (int kk = 0; kk < 8; kk++) {
#pragma unroll
      for (int c = 0; c < Q; c++) {
        float4 a4 = *reinterpret_cast<const float4*>(
            &arow[((kk * Q + c) ^ swz) * 4]);
        float4 w0 = W4[(kk * CIN + 4 * c + 0) * TPN + co4];
        float4 w1 = W4[(kk * CIN + 4 * c + 1) * TPN + co4];
        float4 w2 = W4[(kk * CIN + 4 * c + 2) * TPN + co4];
        float4 w3 = W4[(kk * CIN + 4 * c + 3) * TPN + co4];
        acc.x = fmaf(a4.x, w0.x, acc.x);
        acc.y = fmaf(a4.x, w0.y, acc.y);
        acc.z = fmaf(a4.x, w0.z, acc.z);
        acc.w = fmaf(a4.x, w0.w, acc.w);
        acc.x = fmaf(a4.y, w1.x, acc.x);
        acc.y = fmaf(a4.y, w1.y, acc.y);
        acc.z = fmaf(a4.y, w1.z, acc.z);
        acc.w = fmaf(a4.y, w1.w, acc.w);
        acc.x = fmaf(a4.z, w2.x, acc.x);
        acc.y = fmaf(a4.z, w2.y, acc.y);
        acc.z = fmaf(a4.z, w2.z, acc.z);
        acc.w = fmaf(a4.z, w2.w, acc.w);
        acc.x = fmaf(a4.w, w3.x, acc.x);
        acc.y = fmaf(a4.w, w3.y, acc.y);
        acc.z = fmaf(a4.w, w3.z, acc.z);
        acc.w = fmaf(a4.w, w3.w, acc.w);
      }
    }
  }

  float v[4] = {acc.x, acc.y, acc.z, acc.w};
#pragma unroll
  for (int i = 0; i < 4; i++) {
    float w = v[i] * rc;
    v[i] = w > 0.f ? w : expm1f(w);
  }
  if constexpr (RES) {
    v[0] += rres.x;
    v[1] += rres.y;
    v[2] += rres.z;
    v[3] += rres.w;
  }

  if constexpr (POOL) {
    int cx = (int)floorf(p0 / 16.0f);
    int cy = (int)floorf(p1 / 12.0f);
    int cl = bi * G + cy * GX + cx;
    float* pr = pooled + cl * 32 + co4 * 4;
#pragma unroll
    for (int i = 0; i < 4; i++) atomicMaxFloat(&pr[i], v[i]);
  } else {
    *reinterpret_cast<float4*>(Y + (size_t)n2 * COUT + co4 * 4) =
        make_float4(v[0], v[1], v[2], v[3]);
  }
}

// ================= final FC =================
__global__ __launch_bounds__(256) void fc_kernel(const float* __restrict__ pooled,
                                                 const float* __restrict__ fcw,
                                                 float* __restrict__ out) {
  int b = blockIdx.x >> 1;
  int o = blockIdx.x & 1;
  const float* pb = pooled + b * (G * 32);
  float s = 0.f;
  for (int i = threadIdx.x; i < G * 32; i += 256) {
    float v = pb[i];
    v = isfinite(v) ? v : 0.f;  // untouched cells (0xFF memset -> NaN) -> 0
    s += v * fcw[i * 2 + o];
  }
  __shared__ float red[256];
  red[threadIdx.x] = s;
  __syncthreads();
  for (int st = 128; st > 0; st >>= 1) {
    if (threadIdx.x < st) red[threadIdx.x] += red[threadIdx.x + st];
    __syncthreads();
  }
  if (threadIdx.x == 0) out[b * 2 + o] = red[0];
}

extern "C" void kernel_launch(void* const* d_in, const int* in_sizes, int n_in,
                              void* d_out, int out_size, void* d_ws, size_t ws_size,
                              hipStream_t stream) {
  const float* x     = (const float*)d_in[0];
  const float* pos   = (const float*)d_in[1];
  const float* ea    = (const float*)d_in[2];
  const int*   ei    = (const int*)d_in[3];
  const int*   batch = (const int*)d_in[4];
  const float* fcw   = (const float*)d_in[5];
  const float* w1    = (const float*)d_in[6];
  const float* w2    = (const float*)d_in[7];
  const float* w3    = (const float*)d_in[8];
  const float* w4    = (const float*)d_in[9];
  const float* w5    = (const float*)d_in[10];
  const float* w6    = (const float*)d_in[11];
  const float* w7    = (const float*)d_in[12];
  float* out = (float*)d_out;

  // ---- workspace layout (256B-aligned chunks) ----
  char* ws = (char*)d_ws;
  size_t off = 0;
  auto alloc = [&](size_t bytes) {
    size_t p = off;
    off += (bytes + 255) & ~(size_t)255;
    return ws + p;
  };
  float*  rcnt   = (float*)alloc((size_t)N * 4);
  int*    cnt    = (int*)alloc((size_t)N * 4);
  int*    rowptr = (int*)alloc((size_t)(N + 1) * 4);
  int*    cursor = (int*)alloc((size_t)N * 4);
  int*    bsum   = (int*)alloc(512 * 4);
  int*    boff   = (int*)alloc(512 * 4);
  int2*   sdesc  = (int2*)alloc((size_t)N * 8);
  float4* rec    = (float4*)alloc((size_t)E * 16);
  float*  bufA   = (float*)alloc((size_t)N * 32 * 4);
  float*  bufB   = (float*)alloc((size_t)N * 32 * 4);
  float*  bufC   = (float*)alloc((size_t)N * 32 * 4);
  float*  pooled = (float*)alloc((size_t)B_ * G * 32 * 4);

  // ---- CSR build ----
  hipMemsetAsync(cnt, 0, (size_t)N * 4, stream);
  count_kernel<<<EB, 256, 0, stream>>>(ei, cnt);
  rcnt_kernel<<<NB, 256, 0, stream>>>(cnt, rcnt);
  reduce_cnt<<<NB, 256, 0, stream>>>(cnt, bsum);
  scan_bsum<<<1, 512, 0, stream>>>(bsum, boff);
  write_rowptr<<<NB, 256, 0, stream>>>(cnt, boff, rowptr, cursor, sdesc);
  edge_scatter<<<EB, 256, 0, stream>>>(ei, ea, cursor, rec);

  // ---- pooled init (must precede conv7) ----
  hipMemsetAsync(pooled, 0xFF, (size_t)B_ * G * 32 * 4, stream);

  // ---- conv ladder (graph-local, XCD-swizzled; v6 recovery) ----
  // conv1: 1->8    x -> A        NPB=128
  node_conv_v9<1, 8, false, false><<<N / 128, 256, 0, stream>>>(
      x, w1, rec, sdesc, rcnt, nullptr, bufA, nullptr, nullptr, nullptr);
  // conv2: 8->16   A -> B   (B = h_sc1)   NPB=64
  node_conv_v9<8, 16, false, false><<<N / 64, 256, 0, stream>>>(
      bufA, w2, rec, sdesc, rcnt, nullptr, bufB, nullptr, nullptr, nullptr);
  // conv3: 16->16  B -> C
  node_conv_v9<16, 16, false, false><<<N / 64, 256, 0, stream>>>(
      bufB, w3, rec, sdesc, rcnt, nullptr, bufC, nullptr, nullptr, nullptr);
  // conv4: 16->16  C -> A, + residual B
  node_conv_v9<16, 16, true, false><<<N / 64, 256, 0, stream>>>(
      bufC, w4, rec, sdesc, rcnt, bufB, bufA, nullptr, nullptr, nullptr);
  // conv5: 16->32  A -> C   (C = h_sc2)   NPB=32
  node_conv_v9<16, 32, false, false><<<N / 32, 256, 0, stream>>>(
      bufA, w5, rec, sdesc, rcnt, nullptr, bufC, nullptr, nullptr, nullptr);
  // conv6: 32->32  C -> B
  node_conv_v9<32, 32, false, false><<<N / 32, 256, 0, stream>>>(
      bufC, w6, rec, sdesc, rcnt, nullptr, bufB, nullptr, nullptr, nullptr);
  // conv7: 32->32  B -> (pool), + residual C
  node_conv_v9<32, 32, true, true><<<N / 32, 256, 0, stream>>>(
      bufB, w7, rec, sdesc, rcnt, bufC, nullptr, pos, batch, pooled);

  // ---- FC ----
  fc_kernel<<<B_ * 2, 256, 0, stream>>>(pooled, fcw, out);
}

// Round 15
// 644.438 us; speedup vs baseline: 4.3701x; 4.3701x over previous
//
#include <hip/hip_runtime.h>
#include <math.h>

// ---- static problem config (matches reference) ----
namespace {
constexpr int N  = 102400;   // nodes
constexpr int E  = 819200;   // edges
constexpr int B_ = 16;       // graphs
constexpr int G  = 72;       // voxel cells per graph (8 x 9)
constexpr int GX = 8;
constexpr int NB = N / 256;  // 400 blocks over nodes
constexpr int EB = E / 256;  // 3200 blocks over edges
}

// ================= CSR build =================

__global__ __launch_bounds__(256) void count_kernel(const int* __restrict__ ei,
                                                    int* __restrict__ cnt) {
  int e = blockIdx.x * 256 + threadIdx.x;
  atomicAdd(&cnt[ei[E + e]], 1);
}

__global__ __launch_bounds__(256) void rcnt_kernel(const int* __restrict__ cnt,
                                                   float* __restrict__ rcnt) {
  int n = blockIdx.x * 256 + threadIdx.x;
  rcnt[n] = 1.0f / (float)max(cnt[n], 1);
}

// per-256-chunk sums of cnt
__global__ __launch_bounds__(256) void reduce_cnt(const int* __restrict__ cnt,
                                                  int* __restrict__ bsum) {
  __shared__ int s[256];
  int i = blockIdx.x * 256 + threadIdx.x;
  s[threadIdx.x] = cnt[i];
  __syncthreads();
  for (int st = 128; st > 0; st >>= 1) {
    if (threadIdx.x < st) s[threadIdx.x] += s[threadIdx.x + st];
    __syncthreads();
  }
  if (threadIdx.x == 0) bsum[blockIdx.x] = s[0];
}

// single-block exclusive scan of the NB block sums
__global__ __launch_bounds__(512) void scan_bsum(const int* __restrict__ bsum,
                                                 int* __restrict__ boff) {
  __shared__ int s[512];
  int i = threadIdx.x;
  int v = (i < NB) ? bsum[i] : 0;
  s[i] = v;
  __syncthreads();
  for (int st = 1; st < 512; st <<= 1) {
    int t = (i >= st) ? s[i - st] : 0;
    __syncthreads();
    s[i] += t;
    __syncthreads();
  }
  if (i < NB) boff[i] = s[i] - v;  // exclusive
}

// rowptr[n] = exclusive scan of cnt; cursor = rowptr; sdesc[n] = (beg, end)
__global__ __launch_bounds__(256) void write_rowptr(const int* __restrict__ cnt,
                                                    const int* __restrict__ boff,
                                                    int* __restrict__ rowptr,
                                                    int* __restrict__ cursor,
                                                    int2* __restrict__ sdesc) {
  __shared__ int s[256];
  int i = blockIdx.x * 256 + threadIdx.x;
  int v = cnt[i];
  s[threadIdx.x] = v;
  __syncthreads();
  for (int st = 1; st < 256; st <<= 1) {
    int t = (threadIdx.x >= st) ? s[threadIdx.x - st] : 0;
    __syncthreads();
    s[threadIdx.x] += t;
    __syncthreads();
  }
  int off = boff[blockIdx.x] + s[threadIdx.x] - v;  // exclusive
  rowptr[i] = off;
  cursor[i] = off;
  sdesc[i] = make_int2(off, off + v);
  if (i == N - 1) rowptr[N] = off + v;
}

// scatter edge records (src + clamped pseudo-coords) into CSR order
__global__ __launch_bounds__(256) void edge_scatter(const int* __restrict__ ei,
                                                    const float* __restrict__ ea,
                                                    int* __restrict__ cursor,
                                                    float4* __restrict__ rec) {
  int e = blockIdx.x * 256 + threadIdx.x;
  int src = ei[e];
  int dst = ei[E + e];
  float u0 = fminf(fmaxf(ea[3 * e + 0], 0.f), 1.f);
  float u1 = fminf(fmaxf(ea[3 * e + 1], 0.f), 1.f);
  float u2 = fminf(fmaxf(ea[3 * e + 2], 0.f), 1.f);
  int slot = atomicAdd(&cursor[dst], 1);
  rec[slot] = make_float4(__int_as_float(src), u0, u1, u2);
}

// ================= pooling helper =================
__device__ __forceinline__ void atomicMaxFloat(float* addr, float val) {
  if (val >= 0.f)
    atomicMax(reinterpret_cast<int*>(addr), __float_as_int(val));
  else
    atomicMin(reinterpret_cast<unsigned int*>(addr), __float_as_uint(val));
}

// ====== LDS-bridged factored spline conv (v6 EXACT: round-11 636us baseline) ======
// out[n] = (1/deg) * sum_k ( sum_{e->n} b_k(e) * x_src(e) ) @ W[k]
//
// DO NOT REWRITE THE PHASE-1 CODE SHAPE. Measured evidence:
//  - r11 (this shape: zero-init agg + single FMA-accum lambda): 636us,
//    VGPR 56, FETCH 21MB — no scratch.
//  - r13/r14 (mul-init + basis-array + unconditional slots, with OR without
//    __syncthreads): scratch storm — FETCH 895MB, WRITE 668MB, 2.8ms.
//    Semantically equivalent source is NOT allocator-equivalent.
//  - r12 (ballot-guarded 2nd slot): serialized pipeline, 650us.
// __syncthreads doubles as the scheduling fence; keep it.
template <int CIN, int COUT, bool RES, bool POOL>
__global__ __launch_bounds__(256, 4) void node_conv_v6(
    const float* __restrict__ X, const float* __restrict__ W,
    const float4* __restrict__ rec, const int2* __restrict__ sdesc,
    const float* __restrict__ rcnt, const float* __restrict__ res,
    float* __restrict__ Y, const float* __restrict__ pos,
    const int* __restrict__ batch, float* __restrict__ pooled) {
  constexpr int TPN  = COUT / 4;                    // phase-2 threads per node
  constexpr int NPB  = 256 / TPN;                   // nodes per block
  constexpr int ROWF = (CIN >= 8) ? 8 * CIN : 12;   // LDS floats per node row

  __shared__ float sAgg[NPB * ROWF];

  const int tid  = threadIdx.x;
  const int wave = tid >> 6;
  const int lane = tid & 63;

  // XCD swizzle: consecutive node chunks land on one XCD (L2 locality)
  const int sb = (blockIdx.x & 7) * (gridDim.x >> 3) + (blockIdx.x >> 3);
  const int nbase = sb * NPB;

  // ---- phase-2 epilogue gathers hoisted to top (coalesced) ----
  const int node_l = tid / TPN;
  const int co4 = tid % TPN;
  const int n2 = nbase + node_l;
  const float rc = rcnt[n2];
  float4 rres = make_float4(0.f, 0.f, 0.f, 0.f);
  if constexpr (RES)
    rres = *reinterpret_cast<const float4*>(res + (size_t)n2 * COUT + co4 * 4);
  float p0 = 0.f, p1 = 0.f;
  int bi = 0;
  if constexpr (POOL) {
    p0 = pos[n2 * 3 + 0];
    p1 = pos[n2 * 3 + 1];
    bi = batch[n2];
  }

  // ---------------- phase 1 ----------------
  if constexpr (CIN >= 8) {
    constexpr int QN   = CIN / 4;          // channel quads per row
    constexpr int LPN  = 8 * QN;           // lanes per node
    constexpr int NPW  = 64 / LPN;         // nodes per wave per rep
    constexpr int REPS = NPB / (4 * NPW);  // reps per wave

    const int ci4  = lane % QN;
    const int esub = (lane / QN) & 7;
    const int ns   = lane / LPN;
    const int kstar = ((lane / QN) & 1) * 4 + ((lane / (2 * QN)) & 1) * 2 +
                      ((lane / (4 * QN)) & 1);
    const int slot0 = wave * (REPS * NPW) + ns;  // local slot of rep 0

    auto loadDesc = [&](int rep) -> int2 {
      int r = min(rep, REPS - 1);
      return sdesc[nbase + slot0 + r * NPW];
    };
    auto loadRec = [&](int e) -> float4 { return rec[min(e, E - 1)]; };
    auto loadX = [&](const float4& r) -> float4 {
      int src = __float_as_int(r.x);
      return *(reinterpret_cast<const float4*>(X + (size_t)src * CIN) + ci4);
    };

    // pipeline prologue
    int2 d0 = loadDesc(0);
    int2 d1 = loadDesc(1);
    int2 d2 = loadDesc(2);
    float4 ra0 = loadRec(d0.x + esub), rb0 = loadRec(d0.x + esub + 8);
    float4 ra1 = loadRec(d1.x + esub), rb1 = loadRec(d1.x + esub + 8);
    float4 xa0 = loadX(ra0), xb0 = loadX(rb0);

#pragma unroll 1
    for (int rep = 0; rep < REPS; rep++) {
      // issue next-rep x pair (recs arrived one rep ago)
      float4 xa1 = loadX(ra1), xb1 = loadX(rb1);
      // issue rep+2 rec pair (desc arrived one rep ago)
      float4 ra2 = loadRec(d2.x + esub), rb2 = loadRec(d2.x + esub + 8);
      // issue rep+3 desc
      int2 d3 = loadDesc(rep + 3);

      float agg[32];
#pragma unroll
      for (int i = 0; i < 32; i++) agg[i] = 0.f;

      auto accum = [&](const float4& r, const float4& v, bool valid) {
        float uy = r.y, uz = r.z, uw = r.w;
        float py = 1.f - uy, pz = 1.f - uz, pw = 1.f - uw;
        float g = valid ? 1.f : 0.f;
        float t0 = py * pz * g, t1 = uy * pz * g;
        float t2 = py * uz * g, t3 = uy * uz * g;
        float b[8] = {t0 * pw, t1 * pw, t2 * pw, t3 * pw,
                      t0 * uw, t1 * uw, t2 * uw, t3 * uw};
#pragma unroll
        for (int k = 0; k < 8; k++) {
          agg[k * 4 + 0] = fmaf(b[k], v.x, agg[k * 4 + 0]);
          agg[k * 4 + 1] = fmaf(b[k], v.y, agg[k * 4 + 1]);
          agg[k * 4 + 2] = fmaf(b[k], v.z, agg[k * 4 + 2]);
          agg[k * 4 + 3] = fmaf(b[k], v.w, agg[k * 4 + 3]);
        }
      };

      accum(ra0, xa0, d0.x + esub < d0.y);
      accum(rb0, xb0, d0.x + esub + 8 < d0.y);
      // rare: deg > 16 (P ~ 0.4%), exposed-latency fallback
#pragma unroll 1
      for (int e = d0.x + esub + 16; e < d0.y; e += 8) {
        float4 rr = rec[e];
        float4 xx = loadX(rr);
        accum(rr, xx, true);
      }

      // reduce-and-split over esub bits; payload 32 -> 16 -> 8 -> 4
#pragma unroll
      for (int s = 0; s < 3; s++) {
        const int m = QN << s;
        const int H = 16 >> s;
        bool up = (lane & m) != 0;
#pragma unroll
        for (int i = 0; i < H; i++) {
          float keep = up ? agg[i + H] : agg[i];
          float send = up ? agg[i] : agg[i + H];
          agg[i] = keep + __shfl_xor(send, m, 64);
        }
      }

      const int sl = slot0 + rep * NPW;
      const int idx4 = (kstar * QN + ci4) ^ (sl & 7);  // block swizzle
      *reinterpret_cast<float4*>(&sAgg[sl * ROWF + idx4 * 4]) =
          make_float4(agg[0], agg[1], agg[2], agg[3]);

      // rotate pipeline
      d0 = d1; d1 = d2; d2 = d3;
      ra0 = ra1; rb0 = rb1; ra1 = ra2; rb1 = rb2;
      xa0 = xa1; xb0 = xb1;
    }
  } else {
    // CIN == 1: lane = (node_sub, k); serial edge walk with prefetch
    constexpr int LPN  = 8;
    constexpr int NPW  = 8;
    constexpr int REPS = NPB / (4 * NPW);
    const int ns = lane / LPN;
    const int k  = lane & 7;
    const int slotbase = nbase + wave * (REPS * NPW) + ns;

    int2 seC = sdesc[slotbase];
    int2 seN = (REPS > 1) ? sdesc[slotbase + NPW] : seC;
    float4 rcC = make_float4(0.f, 0.f, 0.f, 0.f);
    bool vC = seC.x < seC.y;
    if (vC) rcC = rec[seC.x];

#pragma unroll 1
    for (int rep = 0; rep < REPS; rep++) {
      bool vN = (rep + 1 < REPS) && (seN.x < seN.y);
      float4 rcN = make_float4(0.f, 0.f, 0.f, 0.f);
      if (vN) rcN = rec[seN.x];
      int2 seNN = (rep + 2 < REPS) ? sdesc[slotbase + (rep + 2) * NPW] : seN;

      float a0 = 0.f;
      if (vC) {
        float4 r = rcC;
        int e = seC.x + 1;
        while (true) {
          bool more = e < seC.y;
          float4 rn = r;
          if (more) rn = rec[e];
          int src = __float_as_int(r.x);
          float f0 = (k & 1) ? r.y : 1.f - r.y;
          float f1 = (k & 2) ? r.z : 1.f - r.z;
          float f2 = (k & 4) ? r.w : 1.f - r.w;
          a0 = fmaf(f0 * f1 * f2, X[src], a0);
          if (!more) break;
          r = rn;
          e++;
        }
      }

      const int sl = wave * (REPS * NPW) + rep * NPW + ns;
      sAgg[sl * ROWF + k] = a0;

      seC = seN;
      seN = seNN;
      vC = vN;
      rcC = rcN;
    }
  }
  __syncthreads();

  // ---------------- phase 2 ----------------
  float4 acc = make_float4(0.f, 0.f, 0.f, 0.f);
  const float4* W4 = reinterpret_cast<const float4*>(W);
  const float* arow = &sAgg[node_l * ROWF];

  if constexpr (CIN == 1) {
#pragma unroll
    for (int kk = 0; kk < 8; kk++) {
      float a = arow[kk];
      float4 w = W4[kk * TPN + co4];
      acc.x = fmaf(a, w.x, acc.x);
      acc.y = fmaf(a, w.y, acc.y);
      acc.z = fmaf(a, w.z, acc.z);
      acc.w = fmaf(a, w.w, acc.w);
    }
  } else {
    constexpr int Q = CIN / 4;
    const int swz = node_l & 7;
#pragma unroll 2
    for (int kk = 0; kk < 8; kk++) {
#pragma unroll
      for (int c = 0; c < Q; c++) {
        float4 a4 = *reinterpret_cast<const float4*>(
            &arow[((kk * Q + c) ^ swz) * 4]);
        float4 w0 = W4[(kk * CIN + 4 * c + 0) * TPN + co4];
        float4 w1 = W4[(kk * CIN + 4 * c + 1) * TPN + co4];
        float4 w2 = W4[(kk * CIN + 4 * c + 2) * TPN + co4];
        float4 w3 = W4[(kk * CIN + 4 * c + 3) * TPN + co4];
        acc.x = fmaf(a4.x, w0.x, acc.x);
        acc.y = fmaf(a4.x, w0.y, acc.y);
        acc.z = fmaf(a4.x, w0.z, acc.z);
        acc.w = fmaf(a4.x, w0.w, acc.w);
        acc.x = fmaf(a4.y, w1.x, acc.x);
        acc.y = fmaf(a4.y, w1.y, acc.y);
        acc.z = fmaf(a4.y, w1.z, acc.z);
        acc.w = fmaf(a4.y, w1.w, acc.w);
        acc.x = fmaf(a4.z, w2.x, acc.x);
        acc.y = fmaf(a4.z, w2.y, acc.y);
        acc.z = fmaf(a4.z, w2.z, acc.z);
        acc.w = fmaf(a4.z, w2.w, acc.w);
        acc.x = fmaf(a4.w, w3.x, acc.x);
        acc.y = fmaf(a4.w, w3.y, acc.y);
        acc.z = fmaf(a4.w, w3.z, acc.z);
        acc.w = fmaf(a4.w, w3.w, acc.w);
      }
    }
  }

  float v[4] = {acc.x, acc.y, acc.z, acc.w};
#pragma unroll
  for (int i = 0; i < 4; i++) {
    float w = v[i] * rc;
    v[i] = w > 0.f ? w : expm1f(w);
  }
  if constexpr (RES) {
    v[0] += rres.x;
    v[1] += rres.y;
    v[2] += rres.z;
    v[3] += rres.w;
  }

  if constexpr (POOL) {
    int cx = (int)floorf(p0 / 16.0f);
    int cy = (int)floorf(p1 / 12.0f);
    int cl = bi * G + cy * GX + cx;
    float* pr = pooled + cl * 32 + co4 * 4;
#pragma unroll
    for (int i = 0; i < 4; i++) atomicMaxFloat(&pr[i], v[i]);
  } else {
    *reinterpret_cast<float4*>(Y + (size_t)n2 * COUT + co4 * 4) =
        make_float4(v[0], v[1], v[2], v[3]);
  }
}

// ================= final FC =================
__global__ __launch_bounds__(256) void fc_kernel(const float* __restrict__ pooled,
                                                 const float* __restrict__ fcw,
                                                 float* __restrict__ out) {
  int b = blockIdx.x >> 1;
  int o = blockIdx.x & 1;
  const float* pb = pooled + b * (G * 32);
  float s = 0.f;
  for (int i = threadIdx.x; i < G * 32; i += 256) {
    float v = pb[i];
    v = isfinite(v) ? v : 0.f;  // untouched cells (0xFF memset -> NaN) -> 0
    s += v * fcw[i * 2 + o];
  }
  __shared__ float red[256];
  red[threadIdx.x] = s;
  __syncthreads();
  for (int st = 128; st > 0; st >>= 1) {
    if (threadIdx.x < st) red[threadIdx.x] += red[threadIdx.x + st];
    __syncthreads();
  }
  if (threadIdx.x == 0) out[b * 2 + o] = red[0];
}

extern "C" void kernel_launch(void* const* d_in, const int* in_sizes, int n_in,
                              void* d_out, int out_size, void* d_ws, size_t ws_size,
                              hipStream_t stream) {
  const float* x     = (const float*)d_in[0];
  const float* pos   = (const float*)d_in[1];
  const float* ea    = (const float*)d_in[2];
  const int*   ei    = (const int*)d_in[3];
  const int*   batch = (const int*)d_in[4];
  const float* fcw   = (const float*)d_in[5];
  const float* w1    = (const float*)d_in[6];
  const float* w2    = (const float*)d_in[7];
  const float* w3    = (const float*)d_in[8];
  const float* w4    = (const float*)d_in[9];
  const float* w5    = (const float*)d_in[10];
  const float* w6    = (const float*)d_in[11];
  const float* w7    = (const float*)d_in[12];
  float* out = (float*)d_out;

  // ---- workspace layout (256B-aligned chunks) ----
  char* ws = (char*)d_ws;
  size_t off = 0;
  auto alloc = [&](size_t bytes) {
    size_t p = off;
    off += (bytes + 255) & ~(size_t)255;
    return ws + p;
  };
  float*  rcnt   = (float*)alloc((size_t)N * 4);
  int*    cnt    = (int*)alloc((size_t)N * 4);
  int*    rowptr = (int*)alloc((size_t)(N + 1) * 4);
  int*    cursor = (int*)alloc((size_t)N * 4);
  int*    bsum   = (int*)alloc(512 * 4);
  int*    boff   = (int*)alloc(512 * 4);
  int2*   sdesc  = (int2*)alloc((size_t)N * 8);
  float4* rec    = (float4*)alloc((size_t)E * 16);
  float*  bufA   = (float*)alloc((size_t)N * 32 * 4);
  float*  bufB   = (float*)alloc((size_t)N * 32 * 4);
  float*  bufC   = (float*)alloc((size_t)N * 32 * 4);
  float*  pooled = (float*)alloc((size_t)B_ * G * 32 * 4);

  // ---- CSR build ----
  hipMemsetAsync(cnt, 0, (size_t)N * 4, stream);
  count_kernel<<<EB, 256, 0, stream>>>(ei, cnt);
  rcnt_kernel<<<NB, 256, 0, stream>>>(cnt, rcnt);
  reduce_cnt<<<NB, 256, 0, stream>>>(cnt, bsum);
  scan_bsum<<<1, 512, 0, stream>>>(bsum, boff);
  write_rowptr<<<NB, 256, 0, stream>>>(cnt, boff, rowptr, cursor, sdesc);
  edge_scatter<<<EB, 256, 0, stream>>>(ei, ea, cursor, rec);

  // ---- pooled init (must precede conv7) ----
  hipMemsetAsync(pooled, 0xFF, (size_t)B_ * G * 32 * 4, stream);

  // ---- conv ladder (graph-local, XCD-swizzled) ----
  // conv1: 1->8    x -> A        NPB=128
  node_conv_v6<1, 8, false, false><<<N / 128, 256, 0, stream>>>(
      x, w1, rec, sdesc, rcnt, nullptr, bufA, nullptr, nullptr, nullptr);
  // conv2: 8->16   A -> B   (B = h_sc1)   NPB=64
  node_conv_v6<8, 16, false, false><<<N / 64, 256, 0, stream>>>(
      bufA, w2, rec, sdesc, rcnt, nullptr, bufB, nullptr, nullptr, nullptr);
  // conv3: 16->16  B -> C
  node_conv_v6<16, 16, false, false><<<N / 64, 256, 0, stream>>>(
      bufB, w3, rec, sdesc, rcnt, nullptr, bufC, nullptr, nullptr, nullptr);
  // conv4: 16->16  C -> A, + residual B
  node_conv_v6<16, 16, true, false><<<N / 64, 256, 0, stream>>>(
      bufC, w4, rec, sdesc, rcnt, bufB, bufA, nullptr, nullptr, nullptr);
  // conv5: 16->32  A -> C   (C = h_sc2)   NPB=32
  node_conv_v6<16, 32, false, false><<<N / 32, 256, 0, stream>>>(
      bufA, w5, rec, sdesc, rcnt, nullptr, bufC, nullptr, nullptr, nullptr);
  // conv6: 32->32  C -> B
  node_conv_v6<32, 32, false, false><<<N / 32, 256, 0, stream>>>(
      bufC, w6, rec, sdesc, rcnt, nullptr, bufB, nullptr, nullptr, nullptr);
  // conv7: 32->32  B -> (pool), + residual C
  node_conv_v6<32, 32, true, true><<<N / 32, 256, 0, stream>>>(
      bufB, w7, rec, sdesc, rcnt, bufC, nullptr, pos, batch, pooled);

  // ---- FC ----
  fc_kernel<<<B_ * 2, 256, 0, stream>>>(pooled, fcw, out);
}